// Round 1
// baseline (299.765 us; speedup 1.0000x reference)
//
#include <hip/hip_runtime.h>
#include <stdint.h>

typedef __bf16 bf16_t;
typedef bf16_t bf16x8 __attribute__((ext_vector_type(8)));
typedef float f32x4 __attribute__((ext_vector_type(4)));
typedef unsigned short u16;

#define MFMA16(a, b, c) __builtin_amdgcn_mfma_f32_16x16x32_bf16((a), (b), (c), 0, 0, 0)

__device__ __forceinline__ u16 f2bf(float f) {
  union { float f; unsigned u; } v; v.f = f;
  unsigned r = v.u + 0x7fffu + ((v.u >> 16) & 1u);
  return (u16)(r >> 16);
}

__device__ __forceinline__ void async_cp16(const void* g, void* l) {
  __builtin_amdgcn_global_load_lds(
      (__attribute__((address_space(1))) void*)(void*)g,
      (__attribute__((address_space(3))) void*)l, 16, 0, 0);
}

// ---------------------------------------------------------------------------
// Kernel 1: pack Wq/Wk/Wv (f32 [1024][128]) into bf16 MFMA B-fragment order.
// Frag (mat, nt, kc32): lane l holds W[kc32*32 + 8*(l>>4)+j][nt*16 + (l&15)].
// Flat: wp[((mat*256 + nt*32 + kc32)*64 + lane)*8 + j]
// ---------------------------------------------------------------------------
__global__ __launch_bounds__(256) void pack_w_k(const float* __restrict__ Wq,
                                                const float* __restrict__ Wk,
                                                const float* __restrict__ Wv,
                                                u16* __restrict__ wp) {
  int t = blockIdx.x * 256 + threadIdx.x;  // 0 .. 49151
  int mat = t >> 14;
  int rr = t & 16383;
  int frag = rr >> 6, lane = rr & 63;
  int nt = frag >> 5, kc = frag & 31;
  const float* W = (mat == 0) ? Wq : ((mat == 1) ? Wk : Wv);
  int k0 = kc * 32 + ((lane >> 4) << 3);
  int col = nt * 16 + (lane & 15);
  union { u16 h[8]; uint4 q; } u_;
#pragma unroll
  for (int j = 0; j < 8; ++j) u_.h[j] = f2bf(W[(size_t)(k0 + j) * 128 + col]);
  *(uint4*)(wp + (size_t)t * 8) = u_.q;  // 16B aligned (t*16 bytes)
}

// ---------------------------------------------------------------------------
// Kernel 2: fused QKV projection.  64 rows/block, 4 waves, K-chunks of 64.
// X chunk staged to swizzled LDS bf16; W frags read from packed global (L2).
// Writes Qb (scaled 1/32) [16384][128] bf16, Kb [16384][128] bf16,
// Vt [4][128][4096] bf16 (transposed V).
// ---------------------------------------------------------------------------
__global__ __launch_bounds__(256, 1) void qkv_k(const float* __restrict__ X,
                                                const u16* __restrict__ wp,
                                                u16* __restrict__ Qb,
                                                u16* __restrict__ Kb,
                                                u16* __restrict__ Vt) {
  __shared__ __align__(16) u16 xs[4096];  // [64 rows][64 k] bf16, XOR-swizzled
  const int tid = threadIdx.x;
  const int w = tid >> 6, lane = tid & 63;
  const int r16 = lane >> 4, c16 = lane & 15;
  const int m0 = blockIdx.x * 64;

  f32x4 acc[4][6];
#pragma unroll
  for (int mt = 0; mt < 4; ++mt)
#pragma unroll
    for (int i = 0; i < 6; ++i) acc[mt][i] = (f32x4){0.f, 0.f, 0.f, 0.f};

  for (int kc = 0; kc < 16; ++kc) {
    // --- stage X chunk [64][64] f32 -> bf16 LDS (swizzled) ---
#pragma unroll
    for (int g2 = 0; g2 < 2; ++g2) {
      int g = tid + g2 * 256;
      int row = g >> 3, col8 = g & 7;
      const float* src = X + (size_t)(m0 + row) * 1024 + kc * 64 + col8 * 8;
      float4 v0 = *(const float4*)src;
      float4 v1 = *(const float4*)(src + 4);
      union { u16 h[8]; uint4 q; } u_;
      u_.h[0] = f2bf(v0.x); u_.h[1] = f2bf(v0.y); u_.h[2] = f2bf(v0.z); u_.h[3] = f2bf(v0.w);
      u_.h[4] = f2bf(v1.x); u_.h[5] = f2bf(v1.y); u_.h[6] = f2bf(v1.z); u_.h[7] = f2bf(v1.w);
      int off = row * 128 + ((col8 * 16) ^ ((row & 7) << 4));
      *(uint4*)((char*)xs + off) = u_.q;
    }
    __syncthreads();
    // --- A fragments from LDS ---
    bf16x8 a[4][2];
#pragma unroll
    for (int mt = 0; mt < 4; ++mt)
#pragma unroll
      for (int ks = 0; ks < 2; ++ks) {
        int row = mt * 16 + c16;
        int off = row * 128 + (((ks * 64) + r16 * 16) ^ ((row & 7) << 4));
        a[mt][ks] = *(const bf16x8*)((const char*)xs + off);
      }
    // --- B frags from packed W (global/L2), MFMA ---
#pragma unroll
    for (int i = 0; i < 6; ++i) {
      int t = w + 4 * i;
      int mat = t >> 3, nt = t & 7;
      const u16* bp = wp + (size_t)mat * 131072 +
                      (size_t)((nt * 32 + kc * 2) * 64 + lane) * 8;
#pragma unroll
      for (int ks = 0; ks < 2; ++ks) {
        bf16x8 b = *(const bf16x8*)(bp + (size_t)ks * 512);
#pragma unroll
        for (int mt = 0; mt < 4; ++mt) acc[mt][i] = MFMA16(a[mt][ks], b, acc[mt][i]);
      }
    }
    __syncthreads();
  }

  // --- epilogue ---
  const int batch = m0 >> 12;
#pragma unroll
  for (int i = 0; i < 6; ++i) {
    int t = w + 4 * i;
    int mat = t >> 3, nt = t & 7;
#pragma unroll
    for (int mt = 0; mt < 4; ++mt) {
      f32x4 v = acc[mt][i];
      if (mat == 2) {
        int d = nt * 16 + c16;
        int nloc = (m0 & 4095) + mt * 16 + r16 * 4;
        union { u16 h[4]; uint2 q; } u_;
#pragma unroll
        for (int r = 0; r < 4; ++r) u_.h[r] = f2bf(v[r]);
        *(uint2*)(Vt + ((size_t)(batch * 128 + d)) * 4096 + nloc) = u_.q;
      } else {
        u16* dstm = (mat == 0) ? Qb : Kb;
        float sc = (mat == 0) ? 0.03125f : 1.0f;  // fold 1/sqrt(1024) into Q
#pragma unroll
        for (int r = 0; r < 4; ++r) {
          int row = m0 + mt * 16 + r16 * 4 + r;
          dstm[(size_t)row * 128 + nt * 16 + c16] = f2bf(v[r] * sc);
        }
      }
    }
  }
}

// ---------------------------------------------------------------------------
// Kernel 3: flash attention.  1 block = 64 q-rows (2 waves x 32 rows), KV
// tiles of 64, double-buffered global_load_lds staging with counted vmcnt.
// LDS: K tiles 2x16KB (rows 256B, swizzled) | Vt tiles 2x16KB (rows 128B,
// swizzled) | P per-wave 4KB (rows 128B, swizzled).  Total 72KB.
// ---------------------------------------------------------------------------
__device__ __forceinline__ void attn_stage(const char* kbase, const char* vbase,
                                           char* smem, int buf, int tid) {
  char* kd = smem + buf * 16384;
  char* vd = smem + 32768 + buf * 16384;
#pragma unroll
  for (int i = 0; i < 8; ++i) {
    int s = i * 2048 + tid * 16;
    int row = s >> 8, cb = s & 255;
    async_cp16(kbase + (size_t)row * 256 + (cb ^ ((row & 7) << 4)), kd + s);
  }
#pragma unroll
  for (int i = 0; i < 8; ++i) {
    int s = i * 2048 + tid * 16;
    int d = s >> 7, cb = s & 127;
    async_cp16(vbase + (size_t)d * 8192 + (cb ^ ((d & 7) << 4)), vd + s);
  }
}

__global__ __launch_bounds__(128, 1) void attn_k(const u16* __restrict__ Qb,
                                                 const u16* __restrict__ Kb,
                                                 const u16* __restrict__ Vt,
                                                 float* __restrict__ Out) {
  __shared__ __align__(16) char smem[73728];
  const int tid = threadIdx.x;
  const int w = tid >> 6, lane = tid & 63;
  const int r16 = lane >> 4, c16 = lane & 15;
  // XCD-aware bijective remap (assumes xcd = bid & 7; correctness-independent)
  int bid = blockIdx.x;
  int xcd = bid & 7, slot = bid >> 3;
  int batch = xcd >> 1;
  int qt = (xcd & 1) * 32 + slot;
  const int q0 = qt * 64;

  const char* kbase = (const char*)Kb + (size_t)(batch * 4096) * 256;
  const char* vbase = (const char*)Vt + (size_t)batch * 1048576;

  // Q fragments (held in registers for the whole kernel), pre-scaled by 1/32
  bf16x8 qa[2][4];
#pragma unroll
  for (int mt = 0; mt < 2; ++mt)
#pragma unroll
    for (int kc = 0; kc < 4; ++kc) {
      const u16* qp = Qb + (size_t)(batch * 4096 + q0 + w * 32 + mt * 16 + c16) * 128 +
                      kc * 32 + r16 * 8;
      qa[mt][kc] = *(const bf16x8*)qp;
    }

  f32x4 acc[2][8];
#pragma unroll
  for (int mt = 0; mt < 2; ++mt)
#pragma unroll
    for (int dt = 0; dt < 8; ++dt) acc[mt][dt] = (f32x4){0.f, 0.f, 0.f, 0.f};
  float mr[2][4], lr[2][4];
#pragma unroll
  for (int mt = 0; mt < 2; ++mt)
#pragma unroll
    for (int r = 0; r < 4; ++r) { mr[mt][r] = -3.0e38f; lr[mt][r] = 0.f; }
  char* pb = smem + 65536 + w * 4096;

  attn_stage(kbase, vbase, smem, 0, tid);

  for (int it = 0; it < 64; ++it) {
    if (it < 63) {
      int kv0n = (it + 1) * 64;
      attn_stage(kbase + (size_t)kv0n * 256, vbase + (size_t)kv0n * 2, smem,
                 (it + 1) & 1, tid);
      asm volatile("s_waitcnt vmcnt(16)" ::: "memory");
    } else {
      asm volatile("s_waitcnt vmcnt(0)" ::: "memory");
    }
    __builtin_amdgcn_s_barrier();
    asm volatile("" ::: "memory");

    const char* kb = smem + (it & 1) * 16384;
    const char* vb = smem + 32768 + (it & 1) * 16384;

    // ---- S = Q K^T (Q pre-scaled) ----
    f32x4 sv[2][4];
#pragma unroll
    for (int nt = 0; nt < 4; ++nt) {
      f32x4 s0 = (f32x4){0.f, 0.f, 0.f, 0.f};
      f32x4 s1 = (f32x4){0.f, 0.f, 0.f, 0.f};
      int row = nt * 16 + c16;
      int swz = (row & 7) << 4;
#pragma unroll
      for (int kc = 0; kc < 4; ++kc) {
        bf16x8 kf = *(const bf16x8*)(kb + row * 256 + ((kc * 64 + r16 * 16) ^ swz));
        s0 = MFMA16(qa[0][kc], kf, s0);
        s1 = MFMA16(qa[1][kc], kf, s1);
      }
      sv[0][nt] = s0; sv[1][nt] = s1;
    }

    // ---- online softmax (rows spread: row = 4*r16 + r, cols = c16) ----
    float al[2][4];
#pragma unroll
    for (int mt = 0; mt < 2; ++mt)
#pragma unroll
      for (int r = 0; r < 4; ++r) {
        float mx = fmaxf(fmaxf(sv[mt][0][r], sv[mt][1][r]),
                         fmaxf(sv[mt][2][r], sv[mt][3][r]));
        mx = fmaxf(mx, __shfl_xor(mx, 1));
        mx = fmaxf(mx, __shfl_xor(mx, 2));
        mx = fmaxf(mx, __shfl_xor(mx, 4));
        mx = fmaxf(mx, __shfl_xor(mx, 8));
        float mnew = fmaxf(mr[mt][r], mx);
        float a_ = __expf(mr[mt][r] - mnew);
        float p0 = __expf(sv[mt][0][r] - mnew);
        float p1 = __expf(sv[mt][1][r] - mnew);
        float p2 = __expf(sv[mt][2][r] - mnew);
        float p3 = __expf(sv[mt][3][r] - mnew);
        int prow = mt * 16 + r16 * 4 + r;
        int pswz = (prow & 7) << 4;
        char* pr = pb + prow * 128;
        *(u16*)(pr + ((c16 * 2 + 0) ^ pswz))  = f2bf(p0);
        *(u16*)(pr + ((c16 * 2 + 32) ^ pswz)) = f2bf(p1);
        *(u16*)(pr + ((c16 * 2 + 64) ^ pswz)) = f2bf(p2);
        *(u16*)(pr + ((c16 * 2 + 96) ^ pswz)) = f2bf(p3);
        float rs = p0 + p1 + p2 + p3;
        rs += __shfl_xor(rs, 1);
        rs += __shfl_xor(rs, 2);
        rs += __shfl_xor(rs, 4);
        rs += __shfl_xor(rs, 8);
        lr[mt][r] = lr[mt][r] * a_ + rs;
        mr[mt][r] = mnew;
        al[mt][r] = a_;
      }
#pragma unroll
    for (int mt = 0; mt < 2; ++mt)
#pragma unroll
      for (int dt = 0; dt < 8; ++dt)
#pragma unroll
        for (int r = 0; r < 4; ++r) acc[mt][dt][r] *= al[mt][r];

    // P(u16 stores) -> A-frag(b128 loads) aliasing fence
    asm volatile("" ::: "memory");

    // ---- O += P V ----
    bf16x8 pa[2][2];
#pragma unroll
    for (int mt = 0; mt < 2; ++mt)
#pragma unroll
      for (int k2 = 0; k2 < 2; ++k2) {
        int prow = mt * 16 + c16;
        pa[mt][k2] = *(const bf16x8*)(pb + prow * 128 +
                                      ((k2 * 64 + r16 * 16) ^ ((prow & 7) << 4)));
      }
#pragma unroll
    for (int dt = 0; dt < 8; ++dt) {
      int vrow = dt * 16 + c16;
      int vswz = (vrow & 7) << 4;
#pragma unroll
      for (int k2 = 0; k2 < 2; ++k2) {
        bf16x8 vf = *(const bf16x8*)(vb + vrow * 128 + ((k2 * 64 + r16 * 16) ^ vswz));
        acc[0][dt] = MFMA16(pa[0][k2], vf, acc[0][dt]);
        acc[1][dt] = MFMA16(pa[1][k2], vf, acc[1][dt]);
      }
    }

    asm volatile("" ::: "memory");
    __builtin_amdgcn_s_barrier();
    asm volatile("" ::: "memory");
  }

  // ---- epilogue: O = acc / l ----
#pragma unroll
  for (int mt = 0; mt < 2; ++mt)
#pragma unroll
    for (int dt = 0; dt < 8; ++dt)
#pragma unroll
      for (int r = 0; r < 4; ++r) {
        int row = batch * 4096 + q0 + w * 32 + mt * 16 + r16 * 4 + r;
        Out[(size_t)row * 128 + dt * 16 + c16] = acc[mt][dt][r] / lr[mt][r];
      }
}

// ---------------------------------------------------------------------------
extern "C" void kernel_launch(void* const* d_in, const int* in_sizes, int n_in,
                              void* d_out, int out_size, void* d_ws, size_t ws_size,
                              hipStream_t stream) {
  const float* X  = (const float*)d_in[0];
  const float* Wq = (const float*)d_in[1];
  const float* Wk = (const float*)d_in[2];
  const float* Wv = (const float*)d_in[3];
  float* Out = (float*)d_out;
  char* ws = (char*)d_ws;
  u16* Qb = (u16*)(ws);                       // 4 MB  bf16 [16384][128] (pre-scaled)
  u16* Kb = (u16*)(ws + (4u << 20));          // 4 MB  bf16 [16384][128]
  u16* Vt = (u16*)(ws + (8u << 20));          // 4 MB  bf16 [4][128][4096]
  u16* Wp = (u16*)(ws + (12u << 20));         // 768 KB packed W frags
  pack_w_k<<<dim3(192), dim3(256), 0, stream>>>(Wq, Wk, Wv, Wp);
  qkv_k<<<dim3(256), dim3(256), 0, stream>>>(X, Wp, Qb, Kb, Vt);
  attn_k<<<dim3(256), dim3(128), 0, stream>>>(Qb, Kb, Vt, Out);
}

// Round 2
// 96.656 us; speedup vs baseline: 3.1013x; 3.1013x over previous
//
#include <hip/hip_runtime.h>
#include <stdint.h>

typedef __bf16 bf16_t;
typedef bf16_t bf16x8 __attribute__((ext_vector_type(8)));
typedef float f32x4 __attribute__((ext_vector_type(4)));
typedef float f32x16 __attribute__((ext_vector_type(16)));
typedef unsigned short u16;
typedef unsigned int u32;

#define MFMA16(a, b, c) __builtin_amdgcn_mfma_f32_16x16x32_bf16((a), (b), (c), 0, 0, 0)
#define MFMA32(a, b, c) __builtin_amdgcn_mfma_f32_32x32x16_bf16((a), (b), (c), 0, 0, 0)

// Q folded scale: log2(e)/sqrt(1024)  (softmax runs in exp2 domain)
#define QSCALE 0.04508422002778633f

__device__ __forceinline__ u16 f2bf(float f) {
  union { float f; unsigned u; } v; v.f = f;
  unsigned r = v.u + 0x7fffu + ((v.u >> 16) & 1u);
  return (u16)(r >> 16);
}

__device__ __forceinline__ void async_cp16(const void* g, void* l) {
  __builtin_amdgcn_global_load_lds(
      (__attribute__((address_space(1))) void*)(void*)g,
      (__attribute__((address_space(3))) void*)l, 16, 0, 0);
}

__device__ __forceinline__ u32 cvtpk(float lo, float hi) {
  u32 r;
  asm("v_cvt_pk_bf16_f32 %0, %1, %2" : "=v"(r) : "v"(lo), "v"(hi));
  return r;
}
// after swap: a.lo stays, a.hi <- b.lo ; b.lo <- a.hi(old), b.hi stays
__device__ __forceinline__ void pl32swap(u32& a, u32& b) {
  asm volatile("v_permlane32_swap_b32 %0, %1" : "+v"(a), "+v"(b));
}

// ---------------------------------------------------------------------------
// Kernel 1: pack Wq/Wk/Wv (f32 [1024][128]) into bf16 MFMA B-fragment order.
// ---------------------------------------------------------------------------
__global__ __launch_bounds__(256) void pack_w_k(const float* __restrict__ Wq,
                                                const float* __restrict__ Wk,
                                                const float* __restrict__ Wv,
                                                u16* __restrict__ wp) {
  int t = blockIdx.x * 256 + threadIdx.x;  // 0 .. 49151
  int mat = t >> 14;
  int rr = t & 16383;
  int frag = rr >> 6, lane = rr & 63;
  int nt = frag >> 5, kc = frag & 31;
  const float* W = (mat == 0) ? Wq : ((mat == 1) ? Wk : Wv);
  int k0 = kc * 32 + ((lane >> 4) << 3);
  int col = nt * 16 + (lane & 15);
  union { u16 h[8]; uint4 q; } u_;
#pragma unroll
  for (int j = 0; j < 8; ++j) u_.h[j] = f2bf(W[(size_t)(k0 + j) * 128 + col]);
  *(uint4*)(wp + (size_t)t * 8) = u_.q;
}

// ---------------------------------------------------------------------------
// Kernel 2: fused QKV projection.  32 rows/block (grid 512 -> 2 blocks/CU).
// Writes Qb (scaled QSCALE) [16384][128] bf16, Kb [16384][128] bf16,
// Vt [4][128][4096] bf16 (transposed V).
// ---------------------------------------------------------------------------
__global__ __launch_bounds__(256) void qkv_k(const float* __restrict__ X,
                                             const u16* __restrict__ wp,
                                             u16* __restrict__ Qb,
                                             u16* __restrict__ Kb,
                                             u16* __restrict__ Vt) {
  __shared__ __align__(16) u16 xs[2048];  // [32 rows][64 k] bf16, swizzled
  const int tid = threadIdx.x;
  const int w = tid >> 6, lane = tid & 63;
  const int r16 = lane >> 4, c16 = lane & 15;
  const int m0 = blockIdx.x * 32;

  f32x4 acc[2][6];
#pragma unroll
  for (int mt = 0; mt < 2; ++mt)
#pragma unroll
    for (int i = 0; i < 6; ++i) acc[mt][i] = (f32x4){0.f, 0.f, 0.f, 0.f};

  const int srow = tid >> 3, scol = tid & 7;
  const float* sbase = X + (size_t)(m0 + srow) * 1024 + scol * 8;
  const int soff = srow * 128 + ((scol * 16) ^ ((srow & 7) << 4));

  for (int kc = 0; kc < 16; ++kc) {
    float4 v0 = *(const float4*)(sbase + kc * 64);
    float4 v1 = *(const float4*)(sbase + kc * 64 + 4);
    union { u16 h[8]; uint4 q; } u_;
    u_.h[0] = f2bf(v0.x); u_.h[1] = f2bf(v0.y); u_.h[2] = f2bf(v0.z); u_.h[3] = f2bf(v0.w);
    u_.h[4] = f2bf(v1.x); u_.h[5] = f2bf(v1.y); u_.h[6] = f2bf(v1.z); u_.h[7] = f2bf(v1.w);
    *(uint4*)((char*)xs + soff) = u_.q;
    __syncthreads();
    bf16x8 a[2][2];
#pragma unroll
    for (int mt = 0; mt < 2; ++mt)
#pragma unroll
      for (int ks = 0; ks < 2; ++ks) {
        int row = mt * 16 + c16;
        int off = row * 128 + (((ks * 64) + r16 * 16) ^ ((row & 7) << 4));
        a[mt][ks] = *(const bf16x8*)((const char*)xs + off);
      }
#pragma unroll
    for (int i = 0; i < 6; ++i) {
      int t = w + 4 * i;
      int mat = t >> 3, nt = t & 7;
      const u16* bp = wp + (size_t)mat * 131072 +
                      (size_t)((nt * 32 + kc * 2) * 64 + lane) * 8;
#pragma unroll
      for (int ks = 0; ks < 2; ++ks) {
        bf16x8 b = *(const bf16x8*)(bp + (size_t)ks * 512);
#pragma unroll
        for (int mt = 0; mt < 2; ++mt) acc[mt][i] = MFMA16(a[mt][ks], b, acc[mt][i]);
      }
    }
    __syncthreads();
  }

  const int batch = m0 >> 12;
#pragma unroll
  for (int i = 0; i < 6; ++i) {
    int t = w + 4 * i;
    int mat = t >> 3, nt = t & 7;
#pragma unroll
    for (int mt = 0; mt < 2; ++mt) {
      f32x4 v = acc[mt][i];
      if (mat == 2) {
        int d = nt * 16 + c16;
        int nloc = (m0 & 4095) + mt * 16 + r16 * 4;
        union { u16 h[4]; uint2 q; } u_;
#pragma unroll
        for (int r = 0; r < 4; ++r) u_.h[r] = f2bf(v[r]);
        *(uint2*)(Vt + ((size_t)(batch * 128 + d)) * 4096 + nloc) = u_.q;
      } else {
        u16* dstm = (mat == 0) ? Qb : Kb;
        float sc = (mat == 0) ? QSCALE : 1.0f;
#pragma unroll
        for (int r = 0; r < 4; ++r) {
          int row = m0 + mt * 16 + r16 * 4 + r;
          dstm[(size_t)row * 128 + nt * 16 + c16] = f2bf(v[r] * sc);
        }
      }
    }
  }
}

// ---------------------------------------------------------------------------
// Kernel 3: flash attention, 32x32x16 MFMA, swapped QK^T (S^T in registers),
// in-register softmax (exp2 domain) + T12 cvt_pk/permlane P-fragments,
// T13 deferred rescale.  4 waves x 32 q-rows = 128 q-rows/block, KV tile 64,
// KV-split across blocks -> partial (O, m, l).
// LDS: K dbuf 2x16KB | V^T dbuf 2x16KB = 64KB -> 2 blocks/CU.
// ---------------------------------------------------------------------------
__device__ __forceinline__ void attn_stage(const char* kp, const char* vp,
                                           char* smem, int buf, int tid) {
  char* kd = smem + buf * 16384;
  char* vd = smem + 32768 + buf * 16384;
#pragma unroll
  for (int i = 0; i < 4; ++i) {  // K tile: 64 rows x 256B
    int s = i * 4096 + tid * 16;
    int row = s >> 8, cb = s & 255;
    async_cp16(kp + (size_t)row * 256 + (cb ^ ((row & 15) << 4)), kd + s);
  }
#pragma unroll
  for (int i = 0; i < 4; ++i) {  // V^T tile: 128 rows x 128B
    int s = i * 4096 + tid * 16;
    int d = s >> 7, cb = s & 127;
    async_cp16(vp + (size_t)d * 8192 + (cb ^ ((d & 7) << 4)), vd + s);
  }
}

__global__ __launch_bounds__(256, 2) void attn_k(const u16* __restrict__ Qb,
                                                 const u16* __restrict__ Kb,
                                                 const u16* __restrict__ Vt,
                                                 float* __restrict__ Opart,
                                                 float2* __restrict__ Ml,
                                                 int nsplit, int chunk) {
  __shared__ __align__(16) char smem[65536];
  const int tid = threadIdx.x;
  const int w = tid >> 6, lane = tid & 63;
  const int l31 = lane & 31, hi = lane >> 5;

  // XCD-locality remap: each XCD owns a contiguous range of linear ids.
  const int B = gridDim.x;  // 128 * nsplit (multiple of 8)
  int xcd = blockIdx.x & 7, idx = blockIdx.x >> 3;
  int linear = xcd * (B >> 3) + idx;
  int g = linear >> 5, qt = linear & 31;      // 32 q-tiles (of 128 rows) per batch
  int batch = g / nsplit, split = g - batch * nsplit;
  const int q0 = qt * 128;
  const int n0 = split * chunk;
  const int T = chunk >> 6;

  const char* kbase = (const char*)Kb + ((size_t)batch * 4096 + n0) * 256;
  const char* vbase = (const char*)Vt + (size_t)batch * 1048576 + (size_t)n0 * 2;

  // Q as MFMA B-operand: lane holds Q[q0+w*32+l31][kc*16 + hi*8 + j]
  bf16x8 qf[8];
  const u16* qrow = Qb + ((size_t)batch * 4096 + q0 + w * 32 + l31) * 128 + hi * 8;
#pragma unroll
  for (int kc = 0; kc < 8; ++kc) qf[kc] = *(const bf16x8*)(qrow + kc * 16);

  f32x16 acc[4];
#pragma unroll
  for (int dt = 0; dt < 4; ++dt)
#pragma unroll
    for (int j = 0; j < 16; ++j) acc[dt][j] = 0.f;
  float mr = -3.0e38f, lr = 0.f;
  const int swzK = (lane & 15) << 4;
  const int swzV = (lane & 7) << 4;

  attn_stage(kbase, vbase, smem, 0, tid);

  for (int t = 0; t < T; ++t) {
    if (t + 1 < T) {
      attn_stage(kbase + (size_t)(t + 1) * 16384, vbase + (size_t)(t + 1) * 128,
                 smem, (t + 1) & 1, tid);
      asm volatile("s_waitcnt vmcnt(8)" ::: "memory");
    } else {
      asm volatile("s_waitcnt vmcnt(0)" ::: "memory");
    }
    __builtin_amdgcn_s_barrier();
    asm volatile("" ::: "memory");
    const char* kb = smem + (t & 1) * 16384;
    const char* vb = smem + 32768 + (t & 1) * 16384;

    // ---- S^T = K Q^T : lane owns q-row l31; 32 scores in sv[0..1] ----
    f32x16 sv[2];
    __builtin_amdgcn_s_setprio(1);
#pragma unroll
    for (int nt = 0; nt < 2; ++nt) {
      f32x16 s = {};
      const char* krow = kb + (nt * 32 + l31) * 256;
#pragma unroll
      for (int kc = 0; kc < 8; ++kc) {
        bf16x8 kf = *(const bf16x8*)(krow + ((kc * 32 + hi * 16) ^ swzK));
        s = MFMA32(kf, qf[kc], s);
      }
      sv[nt] = s;
    }
    __builtin_amdgcn_s_setprio(0);

    // ---- in-register online softmax (exp2 domain) ----
    float m16[16];
#pragma unroll
    for (int i = 0; i < 16; ++i) m16[i] = fmaxf(sv[0][i], sv[1][i]);
#pragma unroll
    for (int st = 8; st > 0; st >>= 1)
#pragma unroll
      for (int i = 0; i < st; ++i) m16[i] = fmaxf(m16[i], m16[i + st]);
    float mx = fmaxf(m16[0], __shfl_xor(m16[0], 32));
    float mold = mr;
    float mnew = (mx > mold + 11.5f) ? mx : mold;  // T13 defer (e^8-equivalent)
    mr = mnew;

    float pr[2][16];
#pragma unroll
    for (int nt = 0; nt < 2; ++nt)
#pragma unroll
      for (int i = 0; i < 16; ++i) pr[nt][i] = exp2f(sv[nt][i] - mnew);
    float s16[16];
#pragma unroll
    for (int i = 0; i < 16; ++i) s16[i] = pr[0][i] + pr[1][i];
#pragma unroll
    for (int st = 8; st > 0; st >>= 1)
#pragma unroll
      for (int i = 0; i < st; ++i) s16[i] += s16[i + st];
    float rs = s16[0] + __shfl_xor(s16[0], 32);

    if (__any(mnew > mold)) {  // rare after warmup: rescale acc by row factor
      float a_ = exp2f(mold - mnew);
      lr *= a_;
#pragma unroll
      for (int r = 0; r < 16; ++r) {
        float aq = __shfl(a_, ((r & 3) + 8 * (r >> 2)) + 4 * hi);
#pragma unroll
        for (int dt = 0; dt < 4; ++dt) acc[dt][r] *= aq;
      }
    }
    lr += rs;

    // ---- P -> bf16 A-fragments fully in-register (T12) ----
    bf16x8 pf[4];
#pragma unroll
    for (int nt = 0; nt < 2; ++nt)
#pragma unroll
      for (int half = 0; half < 2; ++half) {
        const float* p = &pr[nt][half * 8];
        u32 a0 = cvtpk(p[0], p[1]);
        u32 b0 = cvtpk(p[4], p[5]);
        u32 c0 = cvtpk(p[2], p[3]);
        u32 d0 = cvtpk(p[6], p[7]);
        pl32swap(a0, b0);
        pl32swap(c0, d0);
        union { u32 u[4]; bf16x8 v; } pu;
        pu.u[0] = a0; pu.u[1] = c0; pu.u[2] = b0; pu.u[3] = d0;
        pf[nt * 2 + half] = pu.v;
      }

    // ---- O += P V ----
    __builtin_amdgcn_s_setprio(1);
#pragma unroll
    for (int dt = 0; dt < 4; ++dt) {
      const char* vrow = vb + (dt * 32 + l31) * 128;
#pragma unroll
      for (int ks = 0; ks < 4; ++ks) {
        bf16x8 vf = *(const bf16x8*)(vrow + ((ks * 32 + hi * 16) ^ swzV));
        acc[dt] = MFMA32(pf[ks], vf, acc[dt]);
      }
    }
    __builtin_amdgcn_s_setprio(0);

    asm volatile("" ::: "memory");
    __builtin_amdgcn_s_barrier();
    asm volatile("" ::: "memory");
  }

  // ---- epilogue: partial O (unnormalized), m, l ----
  size_t obase = (size_t)split * 16384 + (size_t)batch * 4096 + q0 + w * 32;
#pragma unroll
  for (int dt = 0; dt < 4; ++dt)
#pragma unroll
    for (int r = 0; r < 16; ++r) {
      int qr = (r & 3) + 8 * (r >> 2) + 4 * hi;
      Opart[(obase + qr) * 128 + dt * 32 + l31] = acc[dt][r];
    }
  if (lane < 32)
    Ml[split * 16384 + batch * 4096 + q0 + w * 32 + lane] = make_float2(mr, lr);
}

// ---------------------------------------------------------------------------
// Kernel 4: combine KV-split partials.  One thread = one (q, 4-wide d chunk).
// ---------------------------------------------------------------------------
__global__ __launch_bounds__(256) void reduce_k(const float* __restrict__ Op,
                                                const float2* __restrict__ Ml,
                                                float* __restrict__ Out, int S) {
  int t = blockIdx.x * 256 + threadIdx.x;  // 0 .. 524287
  int q = t >> 5, d4 = (t & 31) << 2;
  float ms[4], ls[4];
  float M = -3.0e38f;
  for (int s = 0; s < S; ++s) {
    float2 v = Ml[s * 16384 + q];
    ms[s] = v.x; ls[s] = v.y;
    M = fmaxf(M, v.x);
  }
  float L = 0.f, o0 = 0.f, o1 = 0.f, o2 = 0.f, o3 = 0.f;
  for (int s = 0; s < S; ++s) {
    float wgt = exp2f(ms[s] - M);
    L += ls[s] * wgt;
    float4 pv = *(const float4*)(Op + ((size_t)s * 16384 + q) * 128 + d4);
    o0 += pv.x * wgt; o1 += pv.y * wgt; o2 += pv.z * wgt; o3 += pv.w * wgt;
  }
  float inv = 1.0f / L;
  float4 r = {o0 * inv, o1 * inv, o2 * inv, o3 * inv};
  *(float4*)(Out + (size_t)q * 128 + d4) = r;
}

// ---------------------------------------------------------------------------
extern "C" void kernel_launch(void* const* d_in, const int* in_sizes, int n_in,
                              void* d_out, int out_size, void* d_ws, size_t ws_size,
                              hipStream_t stream) {
  const float* X  = (const float*)d_in[0];
  const float* Wq = (const float*)d_in[1];
  const float* Wk = (const float*)d_in[2];
  const float* Wv = (const float*)d_in[3];
  float* Out = (float*)d_out;
  char* ws = (char*)d_ws;
  u16* Qb = (u16*)(ws);                 // 4 MB bf16 [16384][128] (scaled)
  u16* Kb = (u16*)(ws + (4u << 20));    // 4 MB bf16 [16384][128]
  u16* Vt = (u16*)(ws + (8u << 20));    // 4 MB bf16 [4][128][4096]
  u16* Wp = (u16*)(ws + (12u << 20));   // 768 KB packed W frags
  const size_t pbase = 13631488ull;     // 13 MB
  int S = 1;
  if (ws_size >= pbase + 4ull * 8519680ull) S = 4;
  else if (ws_size >= pbase + 2ull * 8519680ull) S = 2;
  float* Opart = (float*)(ws + pbase);                              // S*8 MB
  float2* Ml   = (float2*)(ws + pbase + (size_t)S * 8388608ull);    // S*128 KB

  pack_w_k<<<dim3(192), dim3(256), 0, stream>>>(Wq, Wk, Wv, Wp);
  qkv_k<<<dim3(512), dim3(256), 0, stream>>>(X, Wp, Qb, Kb, Vt);
  attn_k<<<dim3(128 * S), dim3(256), 0, stream>>>(Qb, Kb, Vt, Opart, Ml, S, 4096 / S);
  reduce_k<<<dim3(2048), dim3(256), 0, stream>>>(Opart, Ml, Out, S);
}